// Round 1
// baseline (3871.001 us; speedup 1.0000x reference)
//
#include <hip/hip_runtime.h>
#include <hip/hip_bf16.h>
#include <math.h>

#define NUM_NODES 100000
#define EMBED_DIM 128
#define COMP_DIM 64
#define T_STEPS 8
#define NSUB 50000

__device__ __forceinline__ float gelu_exact(float x) {
    return 0.5f * x * (1.0f + erff(x * 0.70710678118654752f));
}

// -------------------- scatter-add: x[t] into node table --------------------
__global__ void scatter_kernel(const float* __restrict__ x_t,
                               const int* __restrict__ idx_t,
                               float* __restrict__ table) {
    int tid = blockIdx.x * 256 + threadIdx.x;     // over NSUB*32 (4 floats each)
    int i = tid >> 5;
    int d4 = (tid & 31) * 4;
    if (i >= NSUB) return;
    int node = idx_t[i];
    const float4 v = *reinterpret_cast<const float4*>(x_t + (size_t)i * EMBED_DIM + d4);
    float* dst = table + (size_t)node * EMBED_DIM + d4;
    atomicAdd(dst + 0, v.x);
    atomicAdd(dst + 1, v.y);
    atomicAdd(dst + 2, v.z);
    atomicAdd(dst + 3, v.w);
}

// -------------------- LN over D=128 (table + bd) -> A_ln --------------------
__global__ void ln_d_kernel(const float* __restrict__ table,
                            const float* __restrict__ bd,
                            const float* __restrict__ g,
                            const float* __restrict__ b,
                            float* __restrict__ out, int rows) {
    int row = blockIdx.x * 4 + (threadIdx.x >> 6);
    int lane = threadIdx.x & 63;
    if (row >= rows) return;
    const float* p = table + (size_t)row * EMBED_DIM;
    const float* q = bd + (size_t)row * EMBED_DIM;
    float v0 = p[lane] + q[lane];
    float v1 = p[lane + 64] + q[lane + 64];
    float s = v0 + v1;
    #pragma unroll
    for (int off = 32; off >= 1; off >>= 1) s += __shfl_xor(s, off);
    float mu = s * (1.0f / 128.0f);
    float d0 = v0 - mu, d1 = v1 - mu;
    float vs = d0 * d0 + d1 * d1;
    #pragma unroll
    for (int off = 32; off >= 1; off >>= 1) vs += __shfl_xor(vs, off);
    float rs = rsqrtf(vs * (1.0f / 128.0f) + 1e-5f);
    float* o = out + (size_t)row * EMBED_DIM;
    o[lane]      = d0 * rs * g[lane]      + b[lane];
    o[lane + 64] = d1 * rs * g[lane + 64] + b[lane + 64];
}

// -------------------- gather + LN over C=64 -> G_ln --------------------
__global__ void gather_ln_kernel(const float* __restrict__ h_t,
                                 const int* __restrict__ idx_t,
                                 const float* __restrict__ g,
                                 const float* __restrict__ b,
                                 float* __restrict__ out, int rows) {
    int row = blockIdx.x * 4 + (threadIdx.x >> 6);
    int lane = threadIdx.x & 63;
    if (row >= rows) return;
    int node = idx_t[row];
    float v = h_t[(size_t)node * COMP_DIM + lane];
    float s = v;
    #pragma unroll
    for (int off = 32; off >= 1; off >>= 1) s += __shfl_xor(s, off);
    float mu = s * (1.0f / 64.0f);
    float d = v - mu;
    float vs = d * d;
    #pragma unroll
    for (int off = 32; off >= 1; off >>= 1) vs += __shfl_xor(vs, off);
    float rs = rsqrtf(vs * (1.0f / 64.0f) + 1e-5f);
    out[(size_t)row * COMP_DIM + lane] = d * rs * g[lane] + b[lane];
}

// -------------------- generic fp32 GEMM: C = act(A[M,K] @ W[K,N] + bias) ----
// BM=128, BN=64, BK=32, 256 threads, micro-tile 8x4 per thread.
template <int ACT>
__global__ void gemm_kernel(const float* __restrict__ A,
                            const float* __restrict__ W,
                            const float* __restrict__ bias,
                            float* __restrict__ Cout,
                            int M, int K, int N) {
    __shared__ float s_a[32][129];   // [k][row], padded
    __shared__ float s_b[32][64];    // [k][col]
    const int row0 = blockIdx.x * 128;
    const int col0 = blockIdx.y * 64;
    const int tid = threadIdx.x;
    const int tx = tid & 15;         // 16 col-groups of 4 cols
    const int ty = tid >> 4;         // 16 row-groups, rows = ty + 16*i

    float acc[8][4];
    #pragma unroll
    for (int i = 0; i < 8; ++i)
        #pragma unroll
        for (int j = 0; j < 4; ++j) acc[i][j] = 0.0f;

    for (int k0 = 0; k0 < K; k0 += 32) {
        // stage A tile (128x32)
        #pragma unroll
        for (int it = 0; it < 16; ++it) {
            int idx = it * 256 + tid;
            int r = idx >> 5, kk = idx & 31;
            int gr = row0 + r;
            float v = 0.0f;
            if (gr < M) v = A[(size_t)gr * K + k0 + kk];
            s_a[kk][r] = v;
        }
        // stage W tile (32x64)
        #pragma unroll
        for (int it = 0; it < 8; ++it) {
            int idx = it * 256 + tid;
            int kk = idx >> 6, c = idx & 63;
            s_b[kk][c] = W[(size_t)(k0 + kk) * N + col0 + c];
        }
        __syncthreads();

        #pragma unroll
        for (int kk = 0; kk < 32; ++kk) {
            float a[8];
            #pragma unroll
            for (int i = 0; i < 8; ++i) a[i] = s_a[kk][ty + 16 * i];
            const float4 bv = *reinterpret_cast<const float4*>(&s_b[kk][tx * 4]);
            const float bjs[4] = {bv.x, bv.y, bv.z, bv.w};
            #pragma unroll
            for (int i = 0; i < 8; ++i)
                #pragma unroll
                for (int j = 0; j < 4; ++j) acc[i][j] = fmaf(a[i], bjs[j], acc[i][j]);
        }
        __syncthreads();
    }

    const int col = col0 + tx * 4;
    const float4 bb = *reinterpret_cast<const float4*>(&bias[col]);
    const float bias4[4] = {bb.x, bb.y, bb.z, bb.w};
    #pragma unroll
    for (int i = 0; i < 8; ++i) {
        int gr = row0 + ty + 16 * i;
        if (gr >= M) continue;
        float4 o;
        float vals[4];
        #pragma unroll
        for (int j = 0; j < 4; ++j) {
            float v = acc[i][j] + bias4[j];
            if (ACT == 1) v = gelu_exact(v);
            vals[j] = v;
        }
        o.x = vals[0]; o.y = vals[1]; o.z = vals[2]; o.w = vals[3];
        *reinterpret_cast<float4*>(&Cout[(size_t)gr * N + col]) = o;
    }
}

extern "C" void kernel_launch(void* const* d_in, const int* in_sizes, int n_in,
                              void* d_out, int out_size, void* d_ws, size_t ws_size,
                              hipStream_t stream) {
    const float* x       = (const float*)d_in[0];
    const int*   indices = (const int*)d_in[1];
    const float* bd      = (const float*)d_in[2];
    const float* ln_d_g  = (const float*)d_in[3];
    const float* ln_d_b  = (const float*)d_in[4];
    const float* Wd1     = (const float*)d_in[5];
    const float* bd1     = (const float*)d_in[6];
    const float* Wd2     = (const float*)d_in[7];
    const float* bd2     = (const float*)d_in[8];
    const float* ln_u_g  = (const float*)d_in[9];
    const float* ln_u_b  = (const float*)d_in[10];
    const float* Wu1     = (const float*)d_in[11];
    const float* bu1     = (const float*)d_in[12];
    const float* Wu2     = (const float*)d_in[13];
    const float* bu2     = (const float*)d_in[14];
    float* out = (float*)d_out;

    // workspace layout (floats), reused per timestep
    float* ws    = (float*)d_ws;
    float* table = ws;                                        // NUM_NODES*128
    float* A_ln  = table + (size_t)NUM_NODES * EMBED_DIM;     // NUM_NODES*128
    float* H     = A_ln  + (size_t)NUM_NODES * EMBED_DIM;     // NUM_NODES*256
    float* h_t   = H     + (size_t)NUM_NODES * 256;           // NUM_NODES*64
    float* G     = h_t   + (size_t)NUM_NODES * COMP_DIM;      // NSUB*64
    float* U     = G     + (size_t)NSUB * COMP_DIM;           // NSUB*128

    const int gemm_rows_d = (NUM_NODES + 127) / 128;  // 782
    const int gemm_rows_u = (NSUB + 127) / 128;       // 391

    for (int t = 0; t < T_STEPS; ++t) {
        const float* x_t   = x + (size_t)t * NSUB * EMBED_DIM;
        const int*   idx_t = indices + (size_t)t * NSUB;
        float*       out_t = out + (size_t)t * NSUB * EMBED_DIM;

        hipMemsetAsync(table, 0, (size_t)NUM_NODES * EMBED_DIM * sizeof(float), stream);
        scatter_kernel<<<(NSUB * 32 + 255) / 256, 256, 0, stream>>>(x_t, idx_t, table);
        ln_d_kernel<<<(NUM_NODES + 3) / 4, 256, 0, stream>>>(table, bd, ln_d_g, ln_d_b,
                                                             A_ln, NUM_NODES);
        gemm_kernel<1><<<dim3(gemm_rows_d, 4), 256, 0, stream>>>(A_ln, Wd1, bd1, H,
                                                                 NUM_NODES, 128, 256);
        gemm_kernel<0><<<dim3(gemm_rows_d, 1), 256, 0, stream>>>(H, Wd2, bd2, h_t,
                                                                 NUM_NODES, 256, 64);
        gather_ln_kernel<<<(NSUB + 3) / 4, 256, 0, stream>>>(h_t, idx_t, ln_u_g, ln_u_b,
                                                             G, NSUB);
        gemm_kernel<1><<<dim3(gemm_rows_u, 2), 256, 0, stream>>>(G, Wu1, bu1, U,
                                                                 NSUB, 64, 128);
        gemm_kernel<0><<<dim3(gemm_rows_u, 2), 256, 0, stream>>>(U, Wu2, bu2, out_t,
                                                                 NSUB, 128, 128);
    }
}

// Round 2
// 1456.236 us; speedup vs baseline: 2.6582x; 2.6582x over previous
//
#include <hip/hip_runtime.h>
#include <math.h>

#define NN 100000
#define DD 128
#define CC 64
#define TT 8
#define NS 50000

typedef __attribute__((ext_vector_type(4))) float f32x4;
typedef __attribute__((ext_vector_type(8))) short bf16x8;

__device__ __forceinline__ short f2bf(float f) {
    union { float f; unsigned u; } v; v.f = f;
    unsigned r = v.u + 0x7fffu + ((v.u >> 16) & 1u);
    return (short)(r >> 16);
}
__device__ __forceinline__ float gelu(float x) {
    return 0.5f * x * (1.0f + erff(x * 0.70710678118654752f));
}

// ---------------- scatter + flag ----------------
__global__ void scatter_kernel(const float* __restrict__ x_t,
                               const int* __restrict__ idx_t,
                               float* __restrict__ table,
                               int* __restrict__ flags) {
    int tid = blockIdx.x * 256 + threadIdx.x;
    int i = tid >> 5;
    if (i >= NS) return;
    int d4 = (tid & 31) * 4;
    int node = idx_t[i];
    if ((tid & 31) == 0) flags[node] = 1;
    float4 v = *reinterpret_cast<const float4*>(x_t + (size_t)i * DD + d4);
    float* dst = table + (size_t)node * DD + d4;
    atomicAdd(dst + 0, v.x); atomicAdd(dst + 1, v.y);
    atomicAdd(dst + 2, v.z); atomicAdd(dst + 3, v.w);
}

// ---------------- compact flagged nodes into list ----------------
__global__ void compact_kernel(int* __restrict__ flags, int* __restrict__ list,
                               int* __restrict__ counter) {
    int i = blockIdx.x * 256 + threadIdx.x;
    if (i >= NN) return;
    if (flags[i]) {
        flags[i] = 0;
        int p = atomicAdd(counter, 1);
        list[p] = i;
    }
}

// ---------------- weight -> MFMA-fragment prearrange (bf16) ----------------
// slot s = (n*KSTEPS + ks)*64 + lane ; 8 bf16: W[ks*32 + (lane>>4)*8 + j][n*16 + (lane&15)]
__global__ void prep_weights(const float* __restrict__ W, short* __restrict__ dst,
                             int KSTEPS, int total, int N) {
    int s = blockIdx.x * 256 + threadIdx.x;
    if (s >= total) return;
    int lane = s & 63;
    int ks = (s >> 6) % KSTEPS;
    int n = s / (64 * KSTEPS);
    int kb = ks * 32 + (lane >> 4) * 8;
    int col = n * 16 + (lane & 15);
    bf16x8 o;
    #pragma unroll
    for (int j = 0; j < 8; ++j) o[j] = f2bf(W[(size_t)(kb + j) * N + col]);
    *(bf16x8*)(dst + (size_t)s * 8) = o;
}

// ---------------- fused mlp_d: LN -> GEMM1+GELU -> GEMM2 (active rows only) ---
// 384 threads = 6 waves, 16 rows/wave. LDS: W1 64KB + W2 32KB + 6*8KB = 144KB.
__global__ __launch_bounds__(384, 1) void mlp_d_kernel(
    float* table, const float* __restrict__ bd,
    const float* __restrict__ lng, const float* __restrict__ lnb,
    const short* __restrict__ pW1, const short* __restrict__ pW2,
    const float* __restrict__ bd1, const float* __restrict__ bd2,
    const int* __restrict__ list, const int* __restrict__ counter,
    float* __restrict__ h_t) {
    __shared__ short sW1[4096 * 8];
    __shared__ short sW2[2048 * 8];
    __shared__ short sAH[6][4096];   // per-wave: A [16][128] in [0,2048), H [16][256] in [0,4096)

    const int tid = threadIdx.x;
    for (int s = tid; s < 4096; s += 384)
        *(bf16x8*)(sW1 + s * 8) = *(const bf16x8*)(pW1 + (size_t)s * 8);
    for (int s = tid; s < 2048; s += 384)
        *(bf16x8*)(sW2 + s * 8) = *(const bf16x8*)(pW2 + (size_t)s * 8);
    __syncthreads();

    const int wave = tid >> 6, lane = tid & 63;
    short* myb = sAH[wave];
    const int arow = lane & 15;
    const int kgrp = lane >> 4;
    const int swa = (arow & 7) << 4;
    const int nrows = counter[0];
    const int nstrips = (nrows + 95) / 96;

    for (int strip = blockIdx.x; strip < nstrips; strip += gridDim.x) {
        const int row0 = strip * 96 + wave * 16;
        // ---- Phase 1: LN (4 lanes/row, 32 cols/lane) -> swizzled bf16 A in myb
        {
            const int r = lane >> 2;
            const int c0 = (lane & 3) * 32;
            const int gi = row0 + r;
            const bool valid = gi < nrows;
            const int node = list[valid ? gi : (nrows - 1)];
            const float* tp = table + (size_t)node * DD + c0;
            const float* bp = bd + (size_t)node * DD + c0;
            float v[32];
            float s1 = 0.f;
            #pragma unroll
            for (int j = 0; j < 8; ++j) {
                float4 a = ((const float4*)tp)[j];
                float4 c = ((const float4*)bp)[j];
                v[j * 4 + 0] = a.x + c.x; v[j * 4 + 1] = a.y + c.y;
                v[j * 4 + 2] = a.z + c.z; v[j * 4 + 3] = a.w + c.w;
                s1 += v[j * 4 + 0] + v[j * 4 + 1] + v[j * 4 + 2] + v[j * 4 + 3];
            }
            s1 += __shfl_xor(s1, 1); s1 += __shfl_xor(s1, 2);
            float mu = s1 * 0.0078125f;
            float s2 = 0.f;
            #pragma unroll
            for (int j = 0; j < 32; ++j) { float d = v[j] - mu; s2 += d * d; }
            s2 += __shfl_xor(s2, 1); s2 += __shfl_xor(s2, 2);
            float rs = rsqrtf(s2 * 0.0078125f + 1e-5f);
            short ov[32];
            #pragma unroll
            for (int j = 0; j < 8; ++j) {
                float4 gv = ((const float4*)(lng + c0))[j];
                float4 bv = ((const float4*)(lnb + c0))[j];
                ov[j * 4 + 0] = f2bf((v[j * 4 + 0] - mu) * rs * gv.x + bv.x);
                ov[j * 4 + 1] = f2bf((v[j * 4 + 1] - mu) * rs * gv.y + bv.y);
                ov[j * 4 + 2] = f2bf((v[j * 4 + 2] - mu) * rs * gv.z + bv.z);
                ov[j * 4 + 3] = f2bf((v[j * 4 + 3] - mu) * rs * gv.w + bv.w);
            }
            const int swr = (r & 7) << 4;
            #pragma unroll
            for (int q = 0; q < 4; ++q) {
                int boff = (c0 * 2 + q * 16) ^ swr;
                *(bf16x8*)(myb + r * 128 + (boff >> 1)) = *(bf16x8*)(ov + q * 8);
            }
            if (valid) {  // re-zero table rows for next timestep
                float4 z = {0.f, 0.f, 0.f, 0.f};
                float* cp = table + (size_t)node * DD + c0;
                #pragma unroll
                for (int j = 0; j < 8; ++j) ((float4*)cp)[j] = z;
            }
        }
        // ---- Phase 2: GEMM1 (16x256, K=128)
        f32x4 acc[16];
        #pragma unroll
        for (int n = 0; n < 16; ++n) acc[n] = (f32x4){0.f, 0.f, 0.f, 0.f};
        #pragma unroll
        for (int ks = 0; ks < 4; ++ks) {
            int boff = (ks * 64 + kgrp * 16) ^ swa;
            bf16x8 af = *(const bf16x8*)(myb + arow * 128 + (boff >> 1));
            #pragma unroll
            for (int n = 0; n < 16; ++n) {
                bf16x8 bf = *(const bf16x8*)(sW1 + (size_t)(((n << 2) | ks) * 64 + lane) * 8);
                acc[n] = __builtin_amdgcn_mfma_f32_16x16x32_bf16(af, bf, acc[n], 0, 0, 0);
            }
        }
        // ---- Phase 3: bias + GELU -> swizzled bf16 H in myb
        #pragma unroll
        for (int n = 0; n < 16; ++n) {
            float bias = bd1[n * 16 + arow];
            #pragma unroll
            for (int rr = 0; rr < 4; ++rr) {
                float vv = gelu(acc[n][rr] + bias);
                int hr = kgrp * 4 + rr;
                int boff = ((n * 16 + arow) * 2) ^ ((hr & 7) << 4);
                myb[hr * 256 + (boff >> 1)] = f2bf(vv);
            }
        }
        // ---- Phase 4: GEMM2 (16x64, K=256)
        f32x4 acc2[4];
        #pragma unroll
        for (int n = 0; n < 4; ++n) acc2[n] = (f32x4){0.f, 0.f, 0.f, 0.f};
        #pragma unroll
        for (int ks = 0; ks < 8; ++ks) {
            int boff = (ks * 64 + kgrp * 16) ^ swa;
            bf16x8 af = *(const bf16x8*)(myb + arow * 256 + (boff >> 1));
            #pragma unroll
            for (int n = 0; n < 4; ++n) {
                bf16x8 bf = *(const bf16x8*)(sW2 + (size_t)(((n << 3) | ks) * 64 + lane) * 8);
                acc2[n] = __builtin_amdgcn_mfma_f32_16x16x32_bf16(af, bf, acc2[n], 0, 0, 0);
            }
        }
        // ---- epilogue: h_t[node] (f32)
        #pragma unroll
        for (int rr = 0; rr < 4; ++rr) {
            int gi2 = row0 + kgrp * 4 + rr;
            if (gi2 < nrows) {
                int node2 = list[gi2];
                #pragma unroll
                for (int n = 0; n < 4; ++n)
                    h_t[(size_t)node2 * CC + n * 16 + arow] = acc2[n][rr] + bd2[n * 16 + arow];
            }
        }
    }
}

// ---------------- fused mlp_u: gather+LN -> GEMM3+GELU -> GEMM4 -------------
// 512 threads = 8 waves, 16 rows/wave (strip=128). LDS: 16+32+8*4 = 80KB.
__global__ __launch_bounds__(512, 4) void mlp_u_kernel(
    const float* __restrict__ h_t, const int* __restrict__ idx_t,
    const float* __restrict__ lng, const float* __restrict__ lnb,
    const short* __restrict__ pW3, const short* __restrict__ pW4,
    const float* __restrict__ bu1, const float* __restrict__ bu2,
    float* __restrict__ out_t) {
    __shared__ short sW3[1024 * 8];
    __shared__ short sW4[2048 * 8];
    __shared__ short sAU[8][2048];   // per-wave: A [16][64] in [0,1024), U [16][128] in [0,2048)

    const int tid = threadIdx.x;
    for (int s = tid; s < 1024; s += 512)
        *(bf16x8*)(sW3 + s * 8) = *(const bf16x8*)(pW3 + (size_t)s * 8);
    for (int s = tid; s < 2048; s += 512)
        *(bf16x8*)(sW4 + s * 8) = *(const bf16x8*)(pW4 + (size_t)s * 8);
    __syncthreads();

    const int wave = tid >> 6, lane = tid & 63;
    short* myb = sAU[wave];
    const int arow = lane & 15;
    const int kgrp = lane >> 4;
    const int swa = (arow & 7) << 4;
    const int nstrips = (NS + 127) / 128;

    for (int strip = blockIdx.x; strip < nstrips; strip += gridDim.x) {
        const int row0 = strip * 128 + wave * 16;
        // ---- gather + LN (4 lanes/row, 16 cols/lane)
        {
            const int r = lane >> 2;
            const int c0 = (lane & 3) * 16;
            const int gi = row0 + r;
            const int srow = gi < NS ? gi : (NS - 1);
            const int node = idx_t[srow];
            const float* hp = h_t + (size_t)node * CC + c0;
            float v[16];
            float s1 = 0.f;
            #pragma unroll
            for (int j = 0; j < 4; ++j) {
                float4 a = ((const float4*)hp)[j];
                v[j * 4 + 0] = a.x; v[j * 4 + 1] = a.y; v[j * 4 + 2] = a.z; v[j * 4 + 3] = a.w;
                s1 += a.x + a.y + a.z + a.w;
            }
            s1 += __shfl_xor(s1, 1); s1 += __shfl_xor(s1, 2);
            float mu = s1 * 0.015625f;
            float s2 = 0.f;
            #pragma unroll
            for (int j = 0; j < 16; ++j) { float d = v[j] - mu; s2 += d * d; }
            s2 += __shfl_xor(s2, 1); s2 += __shfl_xor(s2, 2);
            float rs = rsqrtf(s2 * 0.015625f + 1e-5f);
            short ov[16];
            #pragma unroll
            for (int j = 0; j < 4; ++j) {
                float4 gv = ((const float4*)(lng + c0))[j];
                float4 bv = ((const float4*)(lnb + c0))[j];
                ov[j * 4 + 0] = f2bf((v[j * 4 + 0] - mu) * rs * gv.x + bv.x);
                ov[j * 4 + 1] = f2bf((v[j * 4 + 1] - mu) * rs * gv.y + bv.y);
                ov[j * 4 + 2] = f2bf((v[j * 4 + 2] - mu) * rs * gv.z + bv.z);
                ov[j * 4 + 3] = f2bf((v[j * 4 + 3] - mu) * rs * gv.w + bv.w);
            }
            const int swr = (r & 7) << 4;
            #pragma unroll
            for (int q = 0; q < 2; ++q) {
                int boff = (c0 * 2 + q * 16) ^ swr;
                *(bf16x8*)(myb + r * 64 + (boff >> 1)) = *(bf16x8*)(ov + q * 8);
            }
        }
        // ---- GEMM3 (16x128, K=64)
        f32x4 a3[8];
        #pragma unroll
        for (int n = 0; n < 8; ++n) a3[n] = (f32x4){0.f, 0.f, 0.f, 0.f};
        #pragma unroll
        for (int ks = 0; ks < 2; ++ks) {
            int boff = (ks * 64 + kgrp * 16) ^ swa;
            bf16x8 af = *(const bf16x8*)(myb + arow * 64 + (boff >> 1));
            #pragma unroll
            for (int n = 0; n < 8; ++n) {
                bf16x8 bf = *(const bf16x8*)(sW3 + (size_t)(((n << 1) | ks) * 64 + lane) * 8);
                a3[n] = __builtin_amdgcn_mfma_f32_16x16x32_bf16(af, bf, a3[n], 0, 0, 0);
            }
        }
        // ---- bias + GELU -> U in myb
        #pragma unroll
        for (int n = 0; n < 8; ++n) {
            float bias = bu1[n * 16 + arow];
            #pragma unroll
            for (int rr = 0; rr < 4; ++rr) {
                float vv = gelu(a3[n][rr] + bias);
                int hr = kgrp * 4 + rr;
                int boff = ((n * 16 + arow) * 2) ^ ((hr & 7) << 4);
                myb[hr * 128 + (boff >> 1)] = f2bf(vv);
            }
        }
        // ---- GEMM4 (16x128, K=128)
        f32x4 a4[8];
        #pragma unroll
        for (int n = 0; n < 8; ++n) a4[n] = (f32x4){0.f, 0.f, 0.f, 0.f};
        #pragma unroll
        for (int ks = 0; ks < 4; ++ks) {
            int boff = (ks * 64 + kgrp * 16) ^ swa;
            bf16x8 af = *(const bf16x8*)(myb + arow * 128 + (boff >> 1));
            #pragma unroll
            for (int n = 0; n < 8; ++n) {
                bf16x8 bf = *(const bf16x8*)(sW4 + (size_t)(((n << 2) | ks) * 64 + lane) * 8);
                a4[n] = __builtin_amdgcn_mfma_f32_16x16x32_bf16(af, bf, a4[n], 0, 0, 0);
            }
        }
        // ---- epilogue: out (f32)
        #pragma unroll
        for (int rr = 0; rr < 4; ++rr) {
            int gi2 = row0 + kgrp * 4 + rr;
            if (gi2 < NS) {
                #pragma unroll
                for (int n = 0; n < 8; ++n)
                    out_t[(size_t)gi2 * DD + n * 16 + arow] = a4[n][rr] + bu2[n * 16 + arow];
            }
        }
    }
}

extern "C" void kernel_launch(void* const* d_in, const int* in_sizes, int n_in,
                              void* d_out, int out_size, void* d_ws, size_t ws_size,
                              hipStream_t stream) {
    const float* x       = (const float*)d_in[0];
    const int*   indices = (const int*)d_in[1];
    const float* bd      = (const float*)d_in[2];
    const float* ln_d_g  = (const float*)d_in[3];
    const float* ln_d_b  = (const float*)d_in[4];
    const float* Wd1     = (const float*)d_in[5];
    const float* bd1     = (const float*)d_in[6];
    const float* Wd2     = (const float*)d_in[7];
    const float* bd2     = (const float*)d_in[8];
    const float* ln_u_g  = (const float*)d_in[9];
    const float* ln_u_b  = (const float*)d_in[10];
    const float* Wu1     = (const float*)d_in[11];
    const float* bu1     = (const float*)d_in[12];
    const float* Wu2     = (const float*)d_in[13];
    const float* bu2     = (const float*)d_in[14];
    float* out = (float*)d_out;

    char* ws = (char*)d_ws;
    size_t o = 0;
    auto alloc = [&](size_t bytes) { char* p = ws + o; o = (o + bytes + 255) & ~(size_t)255; return p; };
    float* table   = (float*)alloc((size_t)NN * DD * 4);
    float* h_t     = (float*)alloc((size_t)NN * CC * 4);
    int*   flags   = (int*)alloc((size_t)NN * 4);
    int*   list    = (int*)alloc((size_t)NN * 4);
    int*   cnts    = (int*)alloc(TT * 4);
    short* pW1     = (short*)alloc((size_t)4096 * 16);
    short* pW2     = (short*)alloc((size_t)2048 * 16);
    short* pW3     = (short*)alloc((size_t)1024 * 16);
    short* pW4     = (short*)alloc((size_t)2048 * 16);

    hipMemsetAsync(table, 0, (size_t)NN * DD * 4, stream);
    hipMemsetAsync(flags, 0, (size_t)NN * 4, stream);
    hipMemsetAsync(cnts, 0, TT * 4, stream);

    prep_weights<<<16, 256, 0, stream>>>(Wd1, pW1, 4, 4096, 256);
    prep_weights<<<8, 256, 0, stream>>>(Wd2, pW2, 8, 2048, 64);
    prep_weights<<<4, 256, 0, stream>>>(Wu1, pW3, 2, 1024, 128);
    prep_weights<<<8, 256, 0, stream>>>(Wu2, pW4, 4, 2048, 128);

    for (int t = 0; t < TT; ++t) {
        const float* x_t   = x + (size_t)t * NS * DD;
        const int*   idx_t = indices + (size_t)t * NS;
        float*       out_t = out + (size_t)t * NS * DD;

        scatter_kernel<<<(NS * 32 + 255) / 256, 256, 0, stream>>>(x_t, idx_t, table, flags);
        compact_kernel<<<(NN + 255) / 256, 256, 0, stream>>>(flags, list, cnts + t);
        mlp_d_kernel<<<256, 384, 0, stream>>>(table, bd, ln_d_g, ln_d_b, pW1, pW2,
                                              bd1, bd2, list, cnts + t, h_t);
        mlp_u_kernel<<<391, 512, 0, stream>>>(h_t, idx_t, ln_u_g, ln_u_b, pW3, pW4,
                                              bu1, bu2, out_t);
    }
}